// Round 5
// baseline (367.676 us; speedup 1.0000x reference)
//
#include <hip/hip_runtime.h>
#include <hip/hip_bf16.h>

typedef unsigned short u16;
typedef __bf16 bf16x8 __attribute__((ext_vector_type(8)));
typedef u16   u16x4  __attribute__((ext_vector_type(4)));
typedef float f32x4  __attribute__((ext_vector_type(4)));

#define MFMA16(A,B,C) __builtin_amdgcn_mfma_f32_16x16x32_bf16(A,B,C,0,0,0)

#define B_DIM   128
#define IN_DIM  8192
#define OUT_DIM 4096

__device__ __forceinline__ u16 f2bf(float f){
  __hip_bfloat16 h = __float2bfloat16(f);
  return __builtin_bit_cast(u16, h);
}
__device__ __forceinline__ float bf2f(u16 u){
  __hip_bfloat16 h = __builtin_bit_cast(__hip_bfloat16, u);
  return __bfloat162float(h);
}

// ---------------------------------------------------------------------------
// P0a: x -> x_bf16 [b][in]; Bcat[in][0:128]=bf16(0.99*trace+x); Bcat[in][128:256]=bf16(x)
// ---------------------------------------------------------------------------
__global__ __launch_bounds__(256) void p0a(const float* __restrict__ x,
    const float* __restrict__ trace, u16* __restrict__ xbf,
    u16* __restrict__ Bcat){
  __shared__ u16 sx[64*130];
  __shared__ u16 st[64*130];
  const int in0 = blockIdx.x*64;
  const int tid = threadIdx.x;
  for (int rep=0; rep<32; ++rep){
    int flat = rep*256 + tid;
    int b = flat >> 6, ino = flat & 63;
    size_t gi = (size_t)b*IN_DIM + in0 + ino;
    float xv = x[gi];
    float tv = trace[gi];
    u16 xb = f2bf(xv);
    xbf[gi] = xb;
    sx[ino*130 + b] = xb;
    st[ino*130 + b] = f2bf(__fadd_rn(__fmul_rn(0.99f, tv), xv));
  }
  __syncthreads();
  for (int rep=0; rep<32; ++rep){
    int flat = rep*256 + tid;
    int row = flat >> 7, bc = flat & 127;
    size_t base = (size_t)(in0+row)*256;
    Bcat[base + bc]       = st[row*130 + bc];
    Bcat[base + 128 + bc] = sx[row*130 + bc];
  }
}

// ---------------------------------------------------------------------------
// p_t128: transpose+scale a [128][4096] f32 matrix into Acat[o][kofs..kofs+128) bf16
// scale = coef / (tw*128). Also zero-inits gmax (when non-null).
// ---------------------------------------------------------------------------
__global__ __launch_bounds__(256) void p_t128(const float* __restrict__ src,
    u16* __restrict__ Acat, const int* __restrict__ twp, float coef,
    int kofs, int* __restrict__ gmax){
  __shared__ u16 st[64*130];
  const int o0 = blockIdx.x*64;
  const int tid = threadIdx.x;
  if (gmax != nullptr && blockIdx.x==0 && tid==0) *gmax = 0;
  const float scale = coef / (float)(twp[0]*B_DIM);
  for (int rep=0; rep<32; ++rep){
    int flat = rep*256 + tid;
    int b = flat >> 6, oo = flat & 63;
    float v = src[(size_t)b*OUT_DIM + o0 + oo];
    st[oo*130 + b] = f2bf(v*scale);
  }
  __syncthreads();
  for (int rep=0; rep<32; ++rep){
    int flat = rep*256 + tid;
    int row = flat >> 7, bc = flat & 127;
    Acat[(size_t)(o0+row)*256 + kofs + bc] = st[row*130 + bc];
  }
}

// ---------------------------------------------------------------------------
// K1: i-partials = x @ W^T, split-bf16 (hi/lo) MFMA, split-K x8.
// grid (64 n-tiles, 8 k-chunks), 256 thr. Tile [M=128][N=64], BK=64.
// W converted fp32->hi/lo bf16 in LDS per step. A-frags read direct (L2).
// ---------------------------------------------------------------------------
__global__ __launch_bounds__(256) void k1_gemm(const float* __restrict__ W,
    const u16* __restrict__ xbf, float* __restrict__ part){
  __shared__ __align__(16) u16 whi[64*72];
  __shared__ __align__(16) u16 wlo[64*72];
  const int n0    = blockIdx.x*64;
  const int kc    = blockIdx.y;
  const int kbase = kc*1024;
  const int tid   = threadIdx.x;
  const int lane  = tid & 63, wid = tid >> 6;
  const int m0    = wid*32;
  const int l15   = lane & 15, lg = lane >> 4;

  f32x4 acc[2][4];
  #pragma unroll
  for (int a=0;a<2;++a)
    #pragma unroll
    for (int c=0;c<4;++c){ acc[a][c][0]=0.f; acc[a][c][1]=0.f; acc[a][c][2]=0.f; acc[a][c][3]=0.f; }

  for (int step=0; step<16; ++step){
    const int k0 = kbase + step*64;
    __syncthreads();
    #pragma unroll
    for (int j=0;j<4;++j){
      int q  = tid + 256*j;      // 0..1023 quads of the 64x64 tile
      int r  = q >> 4;           // row (n) 0..63
      int c4 = (q & 15)*4;       // col (k) group
      const float4 wv = *reinterpret_cast<const float4*>(
          &W[(size_t)(n0+r)*IN_DIM + k0 + c4]);
      float comp[4] = {wv.x, wv.y, wv.z, wv.w};
      u16 h[4], l[4];
      #pragma unroll
      for (int e=0;e<4;++e){
        u16 hh = f2bf(comp[e]);
        h[e] = hh;
        l[e] = f2bf(__fsub_rn(comp[e], bf2f(hh)));
      }
      *reinterpret_cast<u16x4*>(&whi[r*72 + c4]) = (u16x4){h[0],h[1],h[2],h[3]};
      *reinterpret_cast<u16x4*>(&wlo[r*72 + c4]) = (u16x4){l[0],l[1],l[2],l[3]};
    }
    __syncthreads();

    bf16x8 af[2][2];
    #pragma unroll
    for (int mi=0;mi<2;++mi)
      #pragma unroll
      for (int ks=0;ks<2;++ks)
        af[mi][ks] = *reinterpret_cast<const bf16x8*>(
            &xbf[(size_t)(m0 + 16*mi + l15)*IN_DIM + k0 + ks*32 + 8*lg]);

    #pragma unroll
    for (int ni=0;ni<4;++ni){
      const int bb = (16*ni + l15)*72 + 8*lg;
      #pragma unroll
      for (int ks=0;ks<2;++ks){
        bf16x8 bh = *reinterpret_cast<const bf16x8*>(&whi[bb + ks*32]);
        bf16x8 bl = *reinterpret_cast<const bf16x8*>(&wlo[bb + ks*32]);
        acc[0][ni] = MFMA16(af[0][ks], bh, acc[0][ni]);
        acc[1][ni] = MFMA16(af[1][ks], bh, acc[1][ni]);
        acc[0][ni] = MFMA16(af[0][ks], bl, acc[0][ni]);
        acc[1][ni] = MFMA16(af[1][ks], bl, acc[1][ni]);
      }
    }
  }
  #pragma unroll
  for (int mi=0;mi<2;++mi)
    #pragma unroll
    for (int ni=0;ni<4;++ni)
      #pragma unroll
      for (int r=0;r<4;++r){
        int row = m0 + 16*mi + 4*lg + r;
        int col = n0 + 16*ni + l15;
        part[((size_t)kc*B_DIM + row)*OUT_DIM + col] = acc[mi][ni][r];
      }
}

// Fixed-order split-K reduction (deterministic).
__global__ __launch_bounds__(256) void r1(const float* __restrict__ part,
    float* __restrict__ iacc){
  int idx = blockIdx.x*256 + threadIdx.x;
  float a = part[idx];
  #pragma unroll
  for (int c=1;c<8;++c) a = __fadd_rn(a, part[(size_t)c*524288 + idx]);
  iacc[idx] = a;
}

// ---------------------------------------------------------------------------
// K2: LIF + WTA + inhibition, one block per batch row.
// ---------------------------------------------------------------------------
__global__ __launch_bounds__(256) void k2_lif(const float* __restrict__ iacc,
    const float* __restrict__ mem, const float* __restrict__ thr,
    const float* __restrict__ wta, float* __restrict__ spikes,
    float* __restrict__ mem_out){
  const int b = blockIdx.x;
  const int tid = threadIdx.x;
  const size_t base = (size_t)b*OUT_DIM;
  float vv[16], pv[16];
  int sm = 0;
  float pmax = -1.f, imax = -3.4e38f;
  #pragma unroll
  for (int j=0;j<16;++j){
    int o = tid + 256*j;
    float ii = iacc[base+o];
    float v  = __fadd_rn(__fmul_rn(mem[base+o], 0.2f), ii);   // no FMA: match np
    bool  s  = (v >= thr[o]);
    float p  = s ? wta[base+o] : 0.f;
    vv[j]=v; pv[j]=p;
    sm |= s ? (1<<j) : 0;
    pmax = fmaxf(pmax, p);
    imax = fmaxf(imax, ii);
  }
  float anyv = (sm!=0) ? 1.f : 0.f;
  #pragma unroll
  for (int off=32; off>=1; off>>=1){
    pmax = fmaxf(pmax, __shfl_xor(pmax, off));
    imax = fmaxf(imax, __shfl_xor(imax, off));
    anyv = fmaxf(anyv, __shfl_xor(anyv, off));
  }
  __shared__ float sp[4], si[4], sa[4];
  int wid = tid>>6, lane = tid&63;
  if (lane==0){ sp[wid]=pmax; si[wid]=imax; sa[wid]=anyv; }
  __syncthreads();
  pmax = fmaxf(fmaxf(sp[0],sp[1]), fmaxf(sp[2],sp[3]));
  imax = fmaxf(fmaxf(si[0],si[1]), fmaxf(si[2],si[3]));
  anyv = fmaxf(fmaxf(sa[0],sa[1]), fmaxf(sa[2],sa[3]));
  float isub = __fmul_rn(1.625f, imax);
  #pragma unroll
  for (int j=0;j<16;++j){
    int o = tid + 256*j;
    bool s   = (sm>>j)&1;
    bool win = s && (pv[j] >= pmax);
    spikes[base+o] = win ? 1.f : 0.f;
    float mv  = s ? 0.f : vv[j];
    float sub = (anyv>0.f && !win) ? isub : 0.f;
    mem_out[base+o] = __fsub_rn(mv, sub);
  }
}

// thr0[o] = threshold + 0.002 * sum_b i*spk ; block/global max via atomicMax(int)
__global__ __launch_bounds__(256) void k3a(const float* __restrict__ iacc,
    const float* __restrict__ spikes, const float* __restrict__ threshold,
    float* __restrict__ thr0, int* __restrict__ gmax){
  const int o = blockIdx.x*256 + threadIdx.x;
  float acc = 0.f;
  for (int b=0;b<B_DIM;++b)
    acc = __fadd_rn(acc, __fmul_rn(iacc[(size_t)b*OUT_DIM+o], spikes[(size_t)b*OUT_DIM+o]));
  float t = __fadd_rn(threshold[o], __fmul_rn(0.002f, acc));
  thr0[o] = t;
  float m = t;
  #pragma unroll
  for (int off=32; off>=1; off>>=1) m = fmaxf(m, __shfl_xor(m, off));
  __shared__ float sm4[4];
  if ((threadIdx.x&63)==0) sm4[threadIdx.x>>6] = m;
  __syncthreads();
  if (threadIdx.x==0){
    m = fmaxf(fmaxf(sm4[0],sm4[1]), fmaxf(sm4[2],sm4[3]));
    atomicMax(gmax, __float_as_int(m));   // t > 0 always -> int order == float order
  }
}

__global__ __launch_bounds__(256) void k3b(const float* __restrict__ thr0,
    const int* __restrict__ gmax, float* __restrict__ thr_out){
  int o = blockIdx.x*256 + threadIdx.x;
  float g  = __int_as_float(*gmax);
  float ex = fmaxf(__fsub_rn(g, 350.f), 0.f);
  thr_out[o] = __fsub_rn(thr0[o], ex);
}

// ---------------------------------------------------------------------------
// K4: dw_total = Acat[4096][256] x Bcat[8192][256]^T (scales pre-folded).
// grid (32 i-tiles, 64 o-tiles), tile [64 o][256 i], 4 waves, no LDS (L2-hot).
// ---------------------------------------------------------------------------
__global__ __launch_bounds__(256) void k4_dw(const u16* __restrict__ Acat,
    const u16* __restrict__ Bcat, float* __restrict__ dw){
  const int it = blockIdx.x;
  const int ot = blockIdx.y;
  const int tid = threadIdx.x;
  const int lane = tid&63, wid = tid>>6;
  const int l15 = lane&15, lg = lane>>4;
  const int o0 = ot*64;
  const int iw = it*256 + wid*64;
  f32x4 acc[4][4];
  #pragma unroll
  for (int a=0;a<4;++a)
    #pragma unroll
    for (int c=0;c<4;++c){ acc[a][c][0]=0.f; acc[a][c][1]=0.f; acc[a][c][2]=0.f; acc[a][c][3]=0.f; }

  const size_t abase = (size_t)(o0 + l15)*256 + 8*lg;
  const size_t bbase = (size_t)(iw + l15)*256 + 8*lg;
  #pragma unroll
  for (int ks=0; ks<8; ++ks){
    const int k = ks*32;
    bf16x8 a[4], bb[4];
    #pragma unroll
    for (int mi=0;mi<4;++mi)
      a[mi] = *reinterpret_cast<const bf16x8*>(&Acat[abase + (size_t)mi*16*256 + k]);
    #pragma unroll
    for (int ni=0;ni<4;++ni)
      bb[ni] = *reinterpret_cast<const bf16x8*>(&Bcat[bbase + (size_t)ni*16*256 + k]);
    #pragma unroll
    for (int mi=0;mi<4;++mi)
      #pragma unroll
      for (int ni=0;ni<4;++ni)
        acc[mi][ni] = MFMA16(a[mi], bb[ni], acc[mi][ni]);
  }
  #pragma unroll
  for (int mi=0;mi<4;++mi)
    #pragma unroll
    for (int ni=0;ni<4;++ni)
      #pragma unroll
      for (int r=0;r<4;++r)
        dw[(size_t)(o0 + 16*mi + 4*lg + r)*IN_DIM + iw + 16*ni + l15] = acc[mi][ni][r];
}

// ---------------------------------------------------------------------------
extern "C" void kernel_launch(void* const* d_in, const int* in_sizes, int n_in,
                              void* d_out, int out_size, void* d_ws, size_t ws_size,
                              hipStream_t stream) {
  (void)in_sizes; (void)n_in; (void)out_size; (void)ws_size;
  const float* x      = (const float*)d_in[0];
  const float* weight = (const float*)d_in[1];
  const float* mem    = (const float*)d_in[2];
  const float* thresh = (const float*)d_in[3];
  const float* trace  = (const float*)d_in[4];
  const float* trace2 = (const float*)d_in[5];
  const float* wta    = (const float*)d_in[6];
  const int*   twp    = (const int*)d_in[7];

  float* out    = (float*)d_out;
  float* spikes = out;                 // [128][4096]
  float* dwout  = out + 524288;        // [4096][8192]
  float* throut = out + 34078720;      // [4096]
  float* memout = out + 34082816;      // [128][4096]

  char* ws = (char*)d_ws;
  float* iacc = (float*)ws;                          // 2 MB
  u16*   xbf  = (u16*)(ws + (2u<<20));               // 2 MB
  u16*   Acat = (u16*)(ws + (4u<<20));               // 2 MB  [4096][256]
  u16*   Bcat = (u16*)(ws + (6u<<20));               // 4 MB  [8192][256]
  float* thr0 = (float*)(ws + (10u<<20));            // 16 KB
  int*   gmax = (int*)(ws + (10u<<20) + 16384);

  float* part = dwout;   // 16 MB split-K partials inside dw region (consumed by r1 before k4)

  p0a<<<dim3(128), dim3(256), 0, stream>>>(x, trace, xbf, Bcat);
  p_t128<<<dim3(64), dim3(256), 0, stream>>>(trace2, Acat, twp, -(0.53f*0.99f), 128, gmax);
  k1_gemm<<<dim3(64,8), dim3(256), 0, stream>>>(weight, xbf, part);
  r1<<<dim3(2048), dim3(256), 0, stream>>>(part, iacc);
  k2_lif<<<dim3(128), dim3(256), 0, stream>>>(iacc, mem, thresh, wta, spikes, memout);
  p_t128<<<dim3(64), dim3(256), 0, stream>>>(spikes, Acat, twp, 0.96f, 0, (int*)nullptr);
  k3a<<<dim3(16), dim3(256), 0, stream>>>(iacc, spikes, thresh, thr0, gmax);
  k3b<<<dim3(16), dim3(256), 0, stream>>>(thr0, gmax, throut);
  k4_dw<<<dim3(32,64), dim3(256), 0, stream>>>(Acat, Bcat, dwout);
}

// Round 6
// 357.856 us; speedup vs baseline: 1.0274x; 1.0274x over previous
//
#include <hip/hip_runtime.h>
#include <hip/hip_bf16.h>

typedef unsigned short u16;
typedef __bf16 bf16x8 __attribute__((ext_vector_type(8)));
typedef u16   u16x4  __attribute__((ext_vector_type(4)));
typedef float f32x4  __attribute__((ext_vector_type(4)));

#define MFMA16(A,B,C) __builtin_amdgcn_mfma_f32_16x16x32_bf16(A,B,C,0,0,0)

#define B_DIM   128
#define IN_DIM  8192
#define OUT_DIM 4096

__device__ __forceinline__ u16 f2bf(float f){
  __hip_bfloat16 h = __float2bfloat16(f);
  return __builtin_bit_cast(u16, h);
}
__device__ __forceinline__ float bf2f(u16 u){
  __hip_bfloat16 h = __builtin_bit_cast(__hip_bfloat16, u);
  return __bfloat162float(h);
}

// ---------------------------------------------------------------------------
// prep: blocks [0,128): x -> xbf (bf16), Bcat[in][0:128]=bf16(0.99*trace+x),
//                       Bcat[in][128:256]=bf16(x)   (tile: 64 in-cols x 128 b)
//       blocks [128,192): trace2 -> Acat[o][128:256] = bf16(-A2*0.99/(tw*B) * t2)
// ---------------------------------------------------------------------------
__global__ __launch_bounds__(256) void prep(const float* __restrict__ x,
    const float* __restrict__ trace, const float* __restrict__ trace2,
    const int* __restrict__ twp, u16* __restrict__ xbf,
    u16* __restrict__ Bcat, u16* __restrict__ Acat){
  __shared__ u16 s0[64*130];
  __shared__ u16 s1[64*130];
  const int tid = threadIdx.x;
  if (blockIdx.x < 128){
    const int in0 = blockIdx.x*64;
    #pragma unroll
    for (int rep=0; rep<8; ++rep){
      int flat = rep*256 + tid;          // 0..2047
      int b = flat >> 4, i4 = (flat & 15)*4;
      size_t gi = (size_t)b*IN_DIM + in0 + i4;
      float4 xv = *reinterpret_cast<const float4*>(&x[gi]);
      float4 tv = *reinterpret_cast<const float4*>(&trace[gi]);
      u16 xb[4];
      #pragma unroll
      for (int e=0;e<4;++e){
        float xe = (&xv.x)[e];
        xb[e] = f2bf(xe);
        s0[(i4+e)*130 + b] = xb[e];
        s1[(i4+e)*130 + b] = f2bf(__fadd_rn(__fmul_rn(0.99f, (&tv.x)[e]), xe));
      }
      *reinterpret_cast<u16x4*>(&xbf[gi]) = (u16x4){xb[0],xb[1],xb[2],xb[3]};
    }
    __syncthreads();
    #pragma unroll
    for (int rep=0; rep<32; ++rep){
      int flat = rep*256 + tid;
      int row = flat >> 7, bc = flat & 127;
      size_t base = (size_t)(in0+row)*256;
      Bcat[base + bc]       = s1[row*130 + bc];
      Bcat[base + 128 + bc] = s0[row*130 + bc];
    }
  } else {
    const int o0 = (blockIdx.x - 128)*64;
    const float scale = -(0.53f*0.99f) / (float)(twp[0]*B_DIM);
    #pragma unroll
    for (int rep=0; rep<8; ++rep){
      int flat = rep*256 + tid;
      int b = flat >> 4, o4 = (flat & 15)*4;
      float4 v = *reinterpret_cast<const float4*>(&trace2[(size_t)b*OUT_DIM + o0 + o4]);
      #pragma unroll
      for (int e=0;e<4;++e) s0[(o4+e)*130 + b] = f2bf((&v.x)[e]*scale);
    }
    __syncthreads();
    #pragma unroll
    for (int rep=0; rep<32; ++rep){
      int flat = rep*256 + tid;
      int row = flat >> 7, bc = flat & 127;
      Acat[(size_t)(o0+row)*256 + 128 + bc] = s0[row*130 + bc];
    }
  }
}

// ---------------------------------------------------------------------------
// t128s: spikes [128][4096] -> Acat[o][0:128] = bf16(A1/(tw*B) * spk)
// ---------------------------------------------------------------------------
__global__ __launch_bounds__(256) void t128s(const float* __restrict__ spikes,
    const int* __restrict__ twp, u16* __restrict__ Acat){
  __shared__ u16 s0[64*130];
  const int o0 = blockIdx.x*64;
  const int tid = threadIdx.x;
  const float scale = 0.96f / (float)(twp[0]*B_DIM);
  #pragma unroll
  for (int rep=0; rep<8; ++rep){
    int flat = rep*256 + tid;
    int b = flat >> 4, o4 = (flat & 15)*4;
    float4 v = *reinterpret_cast<const float4*>(&spikes[(size_t)b*OUT_DIM + o0 + o4]);
    #pragma unroll
    for (int e=0;e<4;++e) s0[(o4+e)*130 + b] = f2bf((&v.x)[e]*scale);
  }
  __syncthreads();
  #pragma unroll
  for (int rep=0; rep<32; ++rep){
    int flat = rep*256 + tid;
    int row = flat >> 7, bc = flat & 127;
    Acat[(size_t)(o0+row)*256 + bc] = s0[row*130 + bc];
  }
}

// ---------------------------------------------------------------------------
// K1: i-partials = x @ W^T, split-bf16 (hi/lo) MFMA, split-K x8.
// grid (128 n-tiles, 8 kc), 256 thr. Tile [M=128][N=32], BK=64. 1024 blocks
// (4/CU). Register-prefetch of next W tile hides HBM latency under MFMA.
// ---------------------------------------------------------------------------
__global__ __launch_bounds__(256) void k1_gemm(const float* __restrict__ W,
    const u16* __restrict__ xbf, float* __restrict__ part){
  __shared__ __align__(16) u16 whi[32*72];
  __shared__ __align__(16) u16 wlo[32*72];
  const int n0    = blockIdx.x*32;
  const int kc    = blockIdx.y;
  const int kbase = kc*1024;
  const int tid   = threadIdx.x;
  const int lane  = tid & 63, wid = tid >> 6;
  const int m0    = wid*32;
  const int l15   = lane & 15, lg = lane >> 4;

  f32x4 acc[2][2];
  #pragma unroll
  for (int a=0;a<2;++a)
    #pragma unroll
    for (int c=0;c<2;++c){ acc[a][c][0]=0.f; acc[a][c][1]=0.f; acc[a][c][2]=0.f; acc[a][c][3]=0.f; }

  const int qr[2] = { (tid)>>4, (tid+256)>>4 };        // rows 0..31
  const int qc[2] = { (tid&15)*4, (tid&15)*4 };        // col groups
  float4 wreg[2];
  #pragma unroll
  for (int j=0;j<2;++j)
    wreg[j] = *reinterpret_cast<const float4*>(
        &W[(size_t)(n0+qr[j])*IN_DIM + kbase + qc[j]]);

  for (int step=0; step<16; ++step){
    const int k0 = kbase + step*64;
    // convert current regs -> LDS
    #pragma unroll
    for (int j=0;j<2;++j){
      u16 h[4], l[4];
      #pragma unroll
      for (int e=0;e<4;++e){
        float c = (&wreg[j].x)[e];
        u16 hh = f2bf(c);
        h[e] = hh;
        l[e] = f2bf(__fsub_rn(c, bf2f(hh)));
      }
      *reinterpret_cast<u16x4*>(&whi[qr[j]*72 + qc[j]]) = (u16x4){h[0],h[1],h[2],h[3]};
      *reinterpret_cast<u16x4*>(&wlo[qr[j]*72 + qc[j]]) = (u16x4){l[0],l[1],l[2],l[3]};
    }
    // prefetch next step (latency overlaps barrier+MFMA phase)
    if (step < 15){
      #pragma unroll
      for (int j=0;j<2;++j)
        wreg[j] = *reinterpret_cast<const float4*>(
            &W[(size_t)(n0+qr[j])*IN_DIM + k0 + 64 + qc[j]]);
    }
    __syncthreads();

    bf16x8 af[2][2];
    #pragma unroll
    for (int mi=0;mi<2;++mi)
      #pragma unroll
      for (int ks=0;ks<2;++ks)
        af[mi][ks] = *reinterpret_cast<const bf16x8*>(
            &xbf[(size_t)(m0 + 16*mi + l15)*IN_DIM + k0 + ks*32 + 8*lg]);

    #pragma unroll
    for (int ni=0;ni<2;++ni){
      const int bb = (16*ni + l15)*72 + 8*lg;
      #pragma unroll
      for (int ks=0;ks<2;++ks){
        bf16x8 bh = *reinterpret_cast<const bf16x8*>(&whi[bb + ks*32]);
        bf16x8 bl = *reinterpret_cast<const bf16x8*>(&wlo[bb + ks*32]);
        acc[0][ni] = MFMA16(af[0][ks], bh, acc[0][ni]);
        acc[1][ni] = MFMA16(af[1][ks], bh, acc[1][ni]);
        acc[0][ni] = MFMA16(af[0][ks], bl, acc[0][ni]);
        acc[1][ni] = MFMA16(af[1][ks], bl, acc[1][ni]);
      }
    }
    __syncthreads();
  }
  #pragma unroll
  for (int mi=0;mi<2;++mi)
    #pragma unroll
    for (int ni=0;ni<2;++ni)
      #pragma unroll
      for (int r=0;r<4;++r){
        int row = m0 + 16*mi + 4*lg + r;
        int col = n0 + 16*ni + l15;
        part[((size_t)kc*B_DIM + row)*OUT_DIM + col] = acc[mi][ni][r];
      }
}

// ---------------------------------------------------------------------------
// K2: fused split-K reduce (fixed order) + LIF + WTA + inhibition.
// One block per batch row, 512 threads, float4 I/O. Writes iacc for k3a.
// ---------------------------------------------------------------------------
__global__ __launch_bounds__(512) void k2_lif(const float* __restrict__ part,
    const float* __restrict__ mem, const float* __restrict__ thr,
    const float* __restrict__ wta, float* __restrict__ spikes,
    float* __restrict__ mem_out, float* __restrict__ iacc){
  const int b = blockIdx.x;
  const int tid = threadIdx.x;
  const size_t base = (size_t)b*OUT_DIM;
  float vv[8], pv[8], ia[8];
  int sm = 0;
  float pmax = -1.f, imax = -3.4e38f;
  #pragma unroll
  for (int j=0;j<2;++j){
    const int o = 4*tid + 2048*j;
    f32x4 a = *reinterpret_cast<const f32x4*>(&part[base + o]);   // kc = 0
    #pragma unroll
    for (int c=1;c<8;++c){
      f32x4 p4 = *reinterpret_cast<const f32x4*>(
          &part[((size_t)c*B_DIM + b)*OUT_DIM + o]);
      #pragma unroll
      for (int e=0;e<4;++e) a[e] = __fadd_rn(a[e], p4[e]);
    }
    *reinterpret_cast<f32x4*>(&iacc[base + o]) = a;
    f32x4 m4 = *reinterpret_cast<const f32x4*>(&mem[base + o]);
    f32x4 t4 = *reinterpret_cast<const f32x4*>(&thr[o]);
    f32x4 w4 = *reinterpret_cast<const f32x4*>(&wta[base + o]);
    #pragma unroll
    for (int e=0;e<4;++e){
      int idx = 4*j + e;
      float ii = a[e];
      float v  = __fadd_rn(__fmul_rn(m4[e], 0.2f), ii);   // no FMA: match np
      bool  s  = (v >= t4[e]);
      float p  = s ? w4[e] : 0.f;
      ia[idx]=ii; vv[idx]=v; pv[idx]=p;
      sm |= s ? (1<<idx) : 0;
      pmax = fmaxf(pmax, p);
      imax = fmaxf(imax, ii);
    }
  }
  (void)ia;
  float anyv = (sm!=0) ? 1.f : 0.f;
  #pragma unroll
  for (int off=32; off>=1; off>>=1){
    pmax = fmaxf(pmax, __shfl_xor(pmax, off));
    imax = fmaxf(imax, __shfl_xor(imax, off));
    anyv = fmaxf(anyv, __shfl_xor(anyv, off));
  }
  __shared__ float sp[8], si[8], sa[8];
  const int wid = tid>>6, lane = tid&63;
  if (lane==0){ sp[wid]=pmax; si[wid]=imax; sa[wid]=anyv; }
  __syncthreads();
  pmax = sp[0]; imax = si[0]; anyv = sa[0];
  #pragma unroll
  for (int k=1;k<8;++k){
    pmax = fmaxf(pmax, sp[k]); imax = fmaxf(imax, si[k]); anyv = fmaxf(anyv, sa[k]);
  }
  const float isub = __fmul_rn(1.625f, imax);
  #pragma unroll
  for (int j=0;j<2;++j){
    const int o = 4*tid + 2048*j;
    f32x4 sp4, mm4;
    #pragma unroll
    for (int e=0;e<4;++e){
      int idx = 4*j + e;
      bool s   = (sm>>idx)&1;
      bool win = s && (pv[idx] >= pmax);
      sp4[e] = win ? 1.f : 0.f;
      float mv  = s ? 0.f : vv[idx];
      float sub = (anyv>0.f && !win) ? isub : 0.f;
      mm4[e] = __fsub_rn(mv, sub);
    }
    *reinterpret_cast<f32x4*>(&spikes[base + o])  = sp4;
    *reinterpret_cast<f32x4*>(&mem_out[base + o]) = mm4;
  }
}

// ---------------------------------------------------------------------------
// K3a: thrpart[bc][o] = sum_{b in 16-chunk} i*spk   (grid 16 x 8 = 128 blocks)
// ---------------------------------------------------------------------------
__global__ __launch_bounds__(256) void k3a(const float* __restrict__ iacc,
    const float* __restrict__ spikes, float* __restrict__ thrpart){
  const int o  = blockIdx.x*256 + threadIdx.x;
  const int bc = blockIdx.y;
  float acc = 0.f;
  #pragma unroll
  for (int bb=0; bb<16; ++bb){
    int b = bc*16 + bb;
    acc = __fadd_rn(acc, __fmul_rn(iacc[(size_t)b*OUT_DIM+o], spikes[(size_t)b*OUT_DIM+o]));
  }
  thrpart[(size_t)bc*OUT_DIM + o] = acc;
}

// ---------------------------------------------------------------------------
// K3bc: single block. thr0 = threshold + 0.002*sum(thrpart, fixed order);
// block-wide max; thr_out = thr0 - max(gmax-350, 0). No atomics needed.
// ---------------------------------------------------------------------------
__global__ __launch_bounds__(1024) void k3bc(const float* __restrict__ thrpart,
    const float* __restrict__ threshold, float* __restrict__ thr_out){
  const int tid = threadIdx.x;
  const int o = tid*4;
  f32x4 s = *reinterpret_cast<const f32x4*>(&thrpart[o]);
  #pragma unroll
  for (int c=1;c<8;++c){
    f32x4 p4 = *reinterpret_cast<const f32x4*>(&thrpart[(size_t)c*OUT_DIM + o]);
    #pragma unroll
    for (int e=0;e<4;++e) s[e] = __fadd_rn(s[e], p4[e]);
  }
  f32x4 t4 = *reinterpret_cast<const f32x4*>(&threshold[o]);
  float t0[4];
  #pragma unroll
  for (int e=0;e<4;++e) t0[e] = __fadd_rn(t4[e], __fmul_rn(0.002f, s[e]));
  float m = fmaxf(fmaxf(t0[0],t0[1]), fmaxf(t0[2],t0[3]));
  #pragma unroll
  for (int off=32; off>=1; off>>=1) m = fmaxf(m, __shfl_xor(m, off));
  __shared__ float sm16[16];
  const int wid = tid>>6, lane = tid&63;
  if (lane==0) sm16[wid] = m;
  __syncthreads();
  float g = sm16[0];
  #pragma unroll
  for (int k=1;k<16;++k) g = fmaxf(g, sm16[k]);
  float ex = fmaxf(__fsub_rn(g, 350.f), 0.f);
  f32x4 outv;
  #pragma unroll
  for (int e=0;e<4;++e) outv[e] = __fsub_rn(t0[e], ex);
  *reinterpret_cast<f32x4*>(&thr_out[o]) = outv;
}

// ---------------------------------------------------------------------------
// K4: dw_total = Acat[4096][256] x Bcat[8192][256]^T (scales pre-folded).
// grid (64 o-tiles, 32 i-tiles), tile [64 o][256 i], 4 waves, no LDS (L2-hot).
// ---------------------------------------------------------------------------
__global__ __launch_bounds__(256) void k4_dw(const u16* __restrict__ Acat,
    const u16* __restrict__ Bcat, float* __restrict__ dw){
  const int ot = blockIdx.x;
  const int it = blockIdx.y;
  const int tid = threadIdx.x;
  const int lane = tid&63, wid = tid>>6;
  const int l15 = lane&15, lg = lane>>4;
  const int o0 = ot*64;
  const int iw = it*256 + wid*64;
  f32x4 acc[4][4];
  #pragma unroll
  for (int a=0;a<4;++a)
    #pragma unroll
    for (int c=0;c<4;++c){ acc[a][c][0]=0.f; acc[a][c][1]=0.f; acc[a][c][2]=0.f; acc[a][c][3]=0.f; }

  const size_t abase = (size_t)(o0 + l15)*256 + 8*lg;
  const size_t bbase = (size_t)(iw + l15)*256 + 8*lg;
  #pragma unroll
  for (int ks=0; ks<8; ++ks){
    const int k = ks*32;
    bf16x8 a[4], bb[4];
    #pragma unroll
    for (int mi=0;mi<4;++mi)
      a[mi] = *reinterpret_cast<const bf16x8*>(&Acat[abase + (size_t)mi*16*256 + k]);
    #pragma unroll
    for (int ni=0;ni<4;++ni)
      bb[ni] = *reinterpret_cast<const bf16x8*>(&Bcat[bbase + (size_t)ni*16*256 + k]);
    #pragma unroll
    for (int mi=0;mi<4;++mi)
      #pragma unroll
      for (int ni=0;ni<4;++ni)
        acc[mi][ni] = MFMA16(a[mi], bb[ni], acc[mi][ni]);
  }
  #pragma unroll
  for (int mi=0;mi<4;++mi)
    #pragma unroll
    for (int ni=0;ni<4;++ni)
      #pragma unroll
      for (int r=0;r<4;++r)
        dw[(size_t)(o0 + 16*mi + 4*lg + r)*IN_DIM + iw + 16*ni + l15] = acc[mi][ni][r];
}

// ---------------------------------------------------------------------------
extern "C" void kernel_launch(void* const* d_in, const int* in_sizes, int n_in,
                              void* d_out, int out_size, void* d_ws, size_t ws_size,
                              hipStream_t stream) {
  (void)in_sizes; (void)n_in; (void)out_size; (void)ws_size;
  const float* x      = (const float*)d_in[0];
  const float* weight = (const float*)d_in[1];
  const float* mem    = (const float*)d_in[2];
  const float* thresh = (const float*)d_in[3];
  const float* trace  = (const float*)d_in[4];
  const float* trace2 = (const float*)d_in[5];
  const float* wta    = (const float*)d_in[6];
  const int*   twp    = (const int*)d_in[7];

  float* out    = (float*)d_out;
  float* spikes = out;                 // [128][4096]
  float* dwout  = out + 524288;        // [4096][8192]
  float* throut = out + 34078720;      // [4096]
  float* memout = out + 34082816;      // [128][4096]

  char* ws = (char*)d_ws;
  float* iacc    = (float*)ws;                       // 2 MB
  u16*   xbf     = (u16*)(ws + (2u<<20));            // 2 MB
  u16*   Acat    = (u16*)(ws + (4u<<20));            // 2 MB  [4096][256]
  u16*   Bcat    = (u16*)(ws + (6u<<20));            // 4 MB  [8192][256]
  float* thrpart = (float*)(ws + (10u<<20));         // 128 KB [8][4096]

  float* part = dwout;   // 16 MB split-K partials in dw region (consumed before k4)

  prep <<<dim3(192),    dim3(256),  0, stream>>>(x, trace, trace2, twp, xbf, Bcat, Acat);
  k1_gemm<<<dim3(128,8),dim3(256),  0, stream>>>(weight, xbf, part);
  k2_lif<<<dim3(128),   dim3(512),  0, stream>>>(part, mem, thresh, wta, spikes, memout, iacc);
  t128s<<<dim3(64),     dim3(256),  0, stream>>>(spikes, twp, Acat);
  k3a  <<<dim3(16,8),   dim3(256),  0, stream>>>(iacc, spikes, thrpart);
  k3bc <<<dim3(1),      dim3(1024), 0, stream>>>(thrpart, thresh, throut);
  k4_dw<<<dim3(64,32),  dim3(256),  0, stream>>>(Acat, Bcat, dwout);
}